// Round 6
// baseline (234.323 us; speedup 1.0000x reference)
//
#include <hip/hip_runtime.h>
#include <hip/hip_bf16.h>
#include <math.h>

typedef __attribute__((ext_vector_type(8))) short short8;
typedef __attribute__((ext_vector_type(4))) float f32x4;
typedef __attribute__((ext_vector_type(4))) int int4v;

#define SCL 0.1803368801111204f   // 0.125 * log2(e): folds softmax scale + exp2 conversion

static __device__ __forceinline__ unsigned short f2bf(float f) {
  unsigned u = __float_as_uint(f);
  u = u + 0x7FFFu + ((u >> 16) & 1u);   // RNE
  return (unsigned short)(u >> 16);
}

// monotonic float<->uint key (no NaNs in data)
static __device__ __forceinline__ unsigned keyof(float x) {
  unsigned u = __float_as_uint(x);
  return (u & 0x80000000u) ? ~u : (u | 0x80000000u);
}
static __device__ __forceinline__ float keyinv(unsigned k) {
  unsigned u = (k & 0x80000000u) ? (k & 0x7FFFFFFFu) : ~k;
  return __uint_as_float(u);
}

// S: f32 [16][256] XOR-swizzled (16KB); P: bf16 [16][512] aliased over the same 16KB.
static __device__ __forceinline__ int saddr(int r, int cc) {
  return (((r << 8) + cc) << 2) ^ ((r & 7) << 4);
}
static __device__ __forceinline__ int paddr(int r, int lc) {
  return ((r << 10) + (lc << 1)) ^ ((r & 7) << 4);
}

// async global->LDS, 16B per lane (m97 pattern)
static __device__ __forceinline__ void gld_lds16(const unsigned short* g, unsigned short* l) {
  __builtin_amdgcn_global_load_lds(
      (const __attribute__((address_space(1))) void*)g,
      (__attribute__((address_space(3))) void*)l, 16, 0, 0);
}

// ---------------- f32 -> bf16, q/k/v fused (8/thread) ----------------
__global__ __launch_bounds__(256) void cvt3_k(const float* __restrict__ q,
                                              const float* __restrict__ k,
                                              const float* __restrict__ v,
                                              unsigned short* __restrict__ oq,
                                              unsigned short* __restrict__ ok,
                                              unsigned short* __restrict__ ov) {
  const int y = blockIdx.y;
  const float* in = (y == 0) ? q : (y == 1) ? k : v;
  unsigned short* out = (y == 0) ? oq : (y == 1) ? ok : ov;
  const int i = blockIdx.x * 256 + threadIdx.x;
  const f32x4* p = (const f32x4*)in + 2 * (size_t)i;
  f32x4 a = p[0], b = p[1];
  short8 r;
  r[0] = (short)f2bf(a[0]); r[1] = (short)f2bf(a[1]);
  r[2] = (short)f2bf(a[2]); r[3] = (short)f2bf(a[3]);
  r[4] = (short)f2bf(b[0]); r[5] = (short)f2bf(b[1]);
  r[6] = (short)f2bf(b[2]); r[7] = (short)f2bf(b[3]);
  ((short8*)out)[i] = r;
}

// ---------------- W [k][n] f32 -> Wt [n][k] bf16, 4 weights fused ----------------
__global__ __launch_bounds__(256) void wtrans4_k(const float* __restrict__ Wq,
                                                 const float* __restrict__ Wk,
                                                 const float* __restrict__ Wv,
                                                 const float* __restrict__ Wo,
                                                 unsigned short* __restrict__ Wqt,
                                                 unsigned short* __restrict__ Wkt,
                                                 unsigned short* __restrict__ Wvt,
                                                 unsigned short* __restrict__ Wot) {
  const int z = blockIdx.z;
  const float* W = (z == 0) ? Wq : (z == 1) ? Wk : (z == 2) ? Wv : Wo;
  unsigned short* Wt = (z == 0) ? Wqt : (z == 1) ? Wkt : (z == 2) ? Wvt : Wot;
  __shared__ float tile[32][33];
  const int tx = threadIdx.x, ty = threadIdx.y;
  const int x0 = blockIdx.x * 32, y0 = blockIdx.y * 32;
#pragma unroll
  for (int j = 0; j < 4; ++j)
    tile[ty + j * 8][tx] = W[(y0 + ty + j * 8) * 1024 + x0 + tx];
  __syncthreads();
#pragma unroll
  for (int j = 0; j < 4; ++j)
    Wt[(x0 + ty + j * 8) * 1024 + (y0 + tx)] = f2bf(tile[tx][ty + j * 8]);
}

// ---------------- 128x128 bf16 MFMA GEMM body (global_load_lds staging) ----------------
// MODE 0: out bf16 [b][h][t][d]; MODE 1: out bf16 [b][h][d][t]; MODE 2: out f32 [m][n]
template <int MODE>
static __device__ __forceinline__ void gemm_body(unsigned short* As, unsigned short* Bs,
                                                 const unsigned short* __restrict__ A,
                                                 const unsigned short* __restrict__ Bt,
                                                 const float* __restrict__ bias,
                                                 void* __restrict__ out) {
  const int tid = threadIdx.x;
  const int lane = tid & 63, w = tid >> 6;
  const int wr = w >> 1, wc = w & 1;
  const int m0 = blockIdx.y * 128, n0 = blockIdx.x * 128;
  const int l15 = lane & 15, l4 = lane >> 4;
  f32x4 acc[4][4] = {};
  const int r0 = tid >> 2, s0 = (tid & 3) * 8;
  const int r1 = r0 + 64;
  const unsigned short* gA0 = A + (m0 + r0) * 1024 + s0;
  const unsigned short* gA1 = A + (m0 + r1) * 1024 + s0;
  const unsigned short* gB0 = Bt + (n0 + r0) * 1024 + s0;
  const unsigned short* gB1 = Bt + (n0 + r1) * 1024 + s0;
  unsigned short* lA0 = As + r0 * 32 + s0;
  unsigned short* lA1 = As + r1 * 32 + s0;
  unsigned short* lB0 = Bs + r0 * 32 + s0;
  unsigned short* lB1 = Bs + r1 * 32 + s0;

  for (int kt = 0; kt < 32; ++kt) {
    const int k0 = kt * 32;
    __syncthreads();
    gld_lds16(gA0 + k0, lA0);
    gld_lds16(gA1 + k0, lA1);
    gld_lds16(gB0 + k0, lB0);
    gld_lds16(gB1 + k0, lB1);
    __syncthreads();
    short8 af[4], bfr[4];
#pragma unroll
    for (int i = 0; i < 4; ++i) {
      af[i]  = *(const short8*)(As + (wr * 64 + i * 16 + l15) * 32 + l4 * 8);
      bfr[i] = *(const short8*)(Bs + (wc * 64 + i * 16 + l15) * 32 + l4 * 8);
    }
#pragma unroll
    for (int i = 0; i < 4; ++i)
#pragma unroll
      for (int j = 0; j < 4; ++j)
        acc[i][j] = __builtin_amdgcn_mfma_f32_16x16x32_bf16(af[i], bfr[j], acc[i][j], 0, 0, 0);
  }
#pragma unroll
  for (int i = 0; i < 4; ++i) {
#pragma unroll
    for (int j = 0; j < 4; ++j) {
      const int n = n0 + wc * 64 + j * 16 + l15;
      const float bv = bias[n];
#pragma unroll
      for (int r = 0; r < 4; ++r) {
        const int m = m0 + wr * 64 + i * 16 + l4 * 4 + r;
        const float v = acc[i][j][r] + bv;
        if (MODE == 2) {
          ((float*)out)[m * 1024 + n] = v;
        } else {
          const int bb = m >> 10, t = m & 1023, hh = n >> 6, dd = n & 63;
          const unsigned short bfv = f2bf(v);
          if (MODE == 0)
            ((unsigned short*)out)[(((bb << 4) + hh) * 1024 + t) * 64 + dd] = bfv;
          else
            ((unsigned short*)out)[(((bb << 4) + hh) * 64 + dd) * 1024 + t] = bfv;
        }
      }
    }
  }
}

__global__ __launch_bounds__(256) void gemm_qkv_k(
    const unsigned short* qbf, const unsigned short* kbf, const unsigned short* vbf,
    const unsigned short* Wqt, const unsigned short* Wkt, const unsigned short* Wvt,
    const float* bq, const float* bk, const float* bv,
    unsigned short* Qh, unsigned short* Kh, unsigned short* Vth) {
  __shared__ unsigned short As[128 * 32], Bs[128 * 32];
  const int z = blockIdx.z;
  const unsigned short* A  = (z == 0) ? qbf : ((z == 1) ? kbf : vbf);
  const unsigned short* Bt = (z == 0) ? Wqt : ((z == 1) ? Wkt : Wvt);
  const float* bias        = (z == 0) ? bq  : ((z == 1) ? bk  : bv);
  if (z == 2) gemm_body<1>(As, Bs, A, Bt, bias, Vth);
  else        gemm_body<0>(As, Bs, A, Bt, bias, z ? Kh : Qh);
}

__global__ __launch_bounds__(256) void gemm_out_k(const unsigned short* Y,
                                                  const unsigned short* Wot,
                                                  const float* bo, float* out) {
  __shared__ unsigned short As[128 * 32], Bs[128 * 32];
  gemm_body<2>(As, Bs, Y, Wot, bo, out);
}

// ---------------- fused attention: QK^T -> exact top-64 -> softmax -> PV ----------------
// grid (64 t-blocks, 16 heads, 4 batch), 512 threads (8 waves), 20.3KB dynamic LDS:
//   [0,16KB): S f32[16][256] chunk (4 chunks), aliased by P bf16[16][512] (2 passes)
//   [16KB..): RED [4][16][17] f32 partials + RED2 [16] f32 row inv-sums
__global__ __launch_bounds__(512, 6) void attn_k(const unsigned short* __restrict__ Q,
                                                 const unsigned short* __restrict__ K,
                                                 const unsigned short* __restrict__ Vt,
                                                 unsigned short* __restrict__ Y) {
  extern __shared__ __align__(16) char smem[];
  const int tid = threadIdx.x, lane = tid & 63, w = tid >> 6;
  const int t0 = (63 - blockIdx.x) * 16;   // heavy blocks first
  const int h = blockIdx.y, b = blockIdx.z;
  const unsigned short* Qp = Q + (((b * 16 + h) * 1024) + t0) * 64;
  const unsigned short* Kh = K + (b * 16 + h) * 65536;
  const unsigned short* Vh = Vt + (b * 16 + h) * 65536;
  const int L = t0 + 16;
  const int Lpad = (L + 31) & ~31;
  const int nCT = L >> 4;
  const int l15 = lane & 15, l4 = lane >> 4;
  float* RED  = (float*)(smem + 16384);
  float* RED2 = (float*)(smem + 16384 + 4352);

  const short8 aq0 = *(const short8*)(Qp + l15 * 64 + l4 * 8);
  const short8 aq1 = *(const short8*)(Qp + l15 * 64 + 32 + l4 * 8);

  // QK^T for 16-col tiles [tlo,thi) into the 256-col S chunk (cols mod 256)
  auto qk_chunk = [&](int tlo, int thi) {
    for (int ct = tlo + w; ct < thi; ct += 8) {
      const int c0 = ct * 16;
      const short8 kb0 = *(const short8*)(Kh + (c0 + l15) * 64 + l4 * 8);
      const short8 kb1 = *(const short8*)(Kh + (c0 + l15) * 64 + 32 + l4 * 8);
      f32x4 acc = {0.f, 0.f, 0.f, 0.f};
      acc = __builtin_amdgcn_mfma_f32_16x16x32_bf16(aq0, kb0, acc, 0, 0, 0);
      acc = __builtin_amdgcn_mfma_f32_16x16x32_bf16(aq1, kb1, acc, 0, 0, 0);
      const int c = c0 + l15, cc = c & 255;
      if (ct == nCT - 1) {           // only the diagonal tile needs masking (wave-uniform)
#pragma unroll
        for (int r = 0; r < 4; ++r) {
          const int row = l4 * 4 + r;
          *(float*)(smem + saddr(row, cc)) = (c <= t0 + row) ? acc[r] * SCL : -INFINITY;
        }
      } else {
#pragma unroll
        for (int r = 0; r < 4; ++r)
          *(float*)(smem + saddr(l4 * 4 + r, cc)) = acc[r] * SCL;
      }
    }
  };

  // per-row: exact top-64 threshold (ballot bisection) + unnormalized exp -> packed bf16
  auto process_row = [&](float (&v)[16], unsigned (&pk)[8], int r, int Lr) {
    float lm = v[0];
#pragma unroll
    for (int i = 1; i < 16; ++i) lm = fmaxf(lm, v[i]);
    float mx = lm, mn = lm;
#pragma unroll
    for (int o = 32; o; o >>= 1) {
      mx = fmaxf(mx, __shfl_xor(mx, o));
      mn = fminf(mn, __shfl_xor(mn, o));
    }
    float thr = -INFINITY;
    if (Lr > 64) {
      // min-of-lane-maxes provably has count >= 64 (64 lane-max positions >= it)
      unsigned lo = (unsigned)__builtin_amdgcn_readfirstlane((int)keyof(mn));
      unsigned hi = (unsigned)__builtin_amdgcn_readfirstlane((int)keyof(mx)) + 1u;
      int cl = Lr, ch = 0;
      int alt = 0;
      while (hi - lo > 1u) {
        const unsigned span = hi - lo;
        unsigned off;
        if (alt) off = span >> 1;
        else {
          const float fr = (float)(cl - 64) / (float)(cl - ch);
          off = (unsigned)(fr * (float)span);
          if (off < 1u) off = 1u;
          if (off > span - 1u) off = span - 1u;
        }
        alt ^= 1;
        const unsigned mid = lo + off;
        const float tm = keyinv(mid);
        int cnt = 0;
#pragma unroll
        for (int i = 0; i < 16; ++i) cnt += (int)__popcll(__ballot(v[i] >= tm));
        if (cnt >= 64) { lo = mid; cl = cnt; if (cnt == 64) break; }
        else { hi = mid; ch = cnt; }
      }
      thr = keyinv(lo);
    }
    float s = 0.f;
#pragma unroll
    for (int i = 0; i < 16; ++i) {
      const float pv = (v[i] >= thr) ? exp2f(v[i] - mx) : 0.f;
      v[i] = pv;
      s += pv;
    }
#pragma unroll
    for (int o = 32; o; o >>= 1) s += __shfl_xor(s, o);
    if (lane == 0) RED2[r] = 1.f / s;
#pragma unroll
    for (int p = 0; p < 8; ++p)
      pk[p] = (unsigned)f2bf(v[2 * p]) | ((unsigned)f2bf(v[2 * p + 1]) << 16);
  };

  // P write for pass p (pairs 4p..4p+3 -> local cols [0,512))
  auto write_P = [&](unsigned (&pk)[8], int r, int p) {
#pragma unroll
    for (int jj = 0; jj < 4; ++jj) {
      const int j = 4 * p + jj;
      const int c = j * 128 + (lane << 1);     // global col
      if (c < Lpad) {
        const int lc = c - 512 * p;
        *(unsigned*)(smem + paddr(r, lc)) = pk[j];
      }
    }
  };

  // ---- phase 1/2a: 4 chunks of 256 cols: QK^T -> LDS -> regs ----
  const int rA = w * 2, rB = rA + 1;
  const int LrA = t0 + rA + 1, LrB = t0 + rB + 1;
  float vA[16], vB[16];
#pragma unroll
  for (int c4 = 0; c4 < 4; ++c4) {
    const int cbase = c4 * 256;
    if (cbase < L) {
      const int tlo = c4 * 16;
      const int thi = (nCT < tlo + 16) ? nCT : (tlo + 16);
      qk_chunk(tlo, thi);
      __syncthreads();
#pragma unroll
      for (int jj = 0; jj < 2; ++jj) {
        const int j = 2 * c4 + jj;
        const int c = j * 128 + (lane << 1);   // global col
        const int cc = c & 255;
        const float2 tA = *(const float2*)(smem + saddr(rA, cc));
        const float2 tB = *(const float2*)(smem + saddr(rB, cc));
        const bool vld = c < L;
        vA[2 * j]     = vld ? tA.x : -INFINITY;
        vA[2 * j + 1] = vld ? tA.y : -INFINITY;
        vB[2 * j]     = vld ? tB.x : -INFINITY;
        vB[2 * j + 1] = vld ? tB.y : -INFINITY;
      }
      __syncthreads();
    } else {
#pragma unroll
      for (int jj = 0; jj < 4; ++jj) {
        vA[4 * c4 + jj] = -INFINITY;
        vB[4 * c4 + jj] = -INFINITY;
      }
    }
  }

  // ---- phase 2b: top-64 + softmax (registers only) ----
  unsigned pkA[8], pkB[8];
  process_row(vA, pkA, rA, LrA);
  process_row(vB, pkB, rB, LrB);

  // ---- phase 3: y = P @ V in up to 2 column passes, K-split over 8 waves ----
  const int nSTall = Lpad >> 5;
  const int nST0 = (nSTall < 16) ? nSTall : 16;
  const int d0 = (w & 3) * 16;
  f32x4 acc = {0.f, 0.f, 0.f, 0.f};

  // pass 0: cols [0, 512)
  write_P(pkA, rA, 0);
  write_P(pkB, rB, 0);
  __syncthreads();
  {
    const int stMid = (nST0 + 1) >> 1;
    const int stLo = (w < 4) ? 0 : stMid;
    const int stHi = (w < 4) ? stMid : nST0;
    for (int st = stLo; st < stHi; ++st) {
      const int sb = st * 32 + l4 * 8;
      const short8 paf = *(const short8*)(smem + paddr(l15, sb));
      const short8 vb = *(const short8*)(Vh + (d0 + l15) * 1024 + sb);
      acc = __builtin_amdgcn_mfma_f32_16x16x32_bf16(paf, vb, acc, 0, 0, 0);
    }
  }
  // pass 1: cols [512, Lpad)
  if (Lpad > 512) {
    __syncthreads();
    write_P(pkA, rA, 1);
    write_P(pkB, rB, 1);
    __syncthreads();
    const int nST1 = nSTall - 16;
    const int stMid = (nST1 + 1) >> 1;
    const int stLo = (w < 4) ? 0 : stMid;
    const int stHi = (w < 4) ? stMid : nST1;
    for (int st = stLo; st < stHi; ++st) {
      const int sb = st * 32 + l4 * 8;
      const short8 paf = *(const short8*)(smem + paddr(l15, sb));
      const short8 vb = *(const short8*)(Vh + (d0 + l15) * 1024 + 512 + sb);
      acc = __builtin_amdgcn_mfma_f32_16x16x32_bf16(paf, vb, acc, 0, 0, 0);
    }
  }

  // ---- reduction + epilogue ----
  if (w >= 4) {
    const int base = (w - 4) * 272 + l15;
#pragma unroll
    for (int r = 0; r < 4; ++r) RED[base + (l4 * 4 + r) * 17] = acc[r];
  }
  __syncthreads();
  if (w < 4) {
    const int base = w * 272 + l15;
    const int d = (h << 6) + d0 + l15;
#pragma unroll
    for (int r = 0; r < 4; ++r) {
      const float inv = RED2[l4 * 4 + r];
      const float vr = (acc[r] + RED[base + (l4 * 4 + r) * 17]) * inv;
      const int tg = t0 + l4 * 4 + r;
      Y[((b << 10) + tg) * 1024 + d] = f2bf(vr);
    }
  }
}

// ---------------- host ----------------
extern "C" void kernel_launch(void* const* d_in, const int* in_sizes, int n_in,
                              void* d_out, int out_size, void* d_ws, size_t ws_size,
                              hipStream_t stream) {
  const float* q  = (const float*)d_in[0];
  const float* k  = (const float*)d_in[1];
  const float* v  = (const float*)d_in[2];
  // d_in[3] = tgt_mask (causal tril) — computed analytically, not read
  const float* Wq = (const float*)d_in[4];
  const float* Wk = (const float*)d_in[5];
  const float* Wv = (const float*)d_in[6];
  const float* Wo = (const float*)d_in[7];
  const float* bq = (const float*)d_in[8];
  const float* bk = (const float*)d_in[9];
  const float* bv = (const float*)d_in[10];
  const float* bo = (const float*)d_in[11];

  char* ws = (char*)d_ws;
  const size_t MB = 1u << 20;
  unsigned short* qbf = (unsigned short*)(ws + 0 * MB);   // 8MB; reused as Y later
  unsigned short* kbf = (unsigned short*)(ws + 8 * MB);   // 8MB
  unsigned short* vbf = (unsigned short*)(ws + 16 * MB);  // 8MB
  unsigned short* Wqt = (unsigned short*)(ws + 24 * MB);  // 2MB
  unsigned short* Wkt = (unsigned short*)(ws + 26 * MB);  // 2MB
  unsigned short* Wvt = (unsigned short*)(ws + 28 * MB);  // 2MB
  unsigned short* Wot = (unsigned short*)(ws + 30 * MB);  // 2MB
  unsigned short* Qh  = (unsigned short*)(ws + 32 * MB);  // 8MB [b][h][t][d]
  unsigned short* Kh  = (unsigned short*)(ws + 40 * MB);  // 8MB [b][h][t][d]
  unsigned short* Vth = (unsigned short*)(ws + 48 * MB);  // 8MB [b][h][d][t]
  unsigned short* Y   = qbf;  // alias: qbf is dead after gemm_qkv_k

  cvt3_k<<<dim3(2048, 3), 256, 0, stream>>>(q, k, v, qbf, kbf, vbf);
  wtrans4_k<<<dim3(32, 32, 4), dim3(32, 8), 0, stream>>>(Wq, Wk, Wv, Wo, Wqt, Wkt, Wvt, Wot);
  gemm_qkv_k<<<dim3(8, 32, 3), 256, 0, stream>>>(qbf, kbf, vbf, Wqt, Wkt, Wvt,
                                                 bq, bk, bv, Qh, Kh, Vth);
  attn_k<<<dim3(64, 16, 4), 512, 20800, stream>>>(Qh, Kh, Vth, Y);
  gemm_out_k<<<dim3(8, 32), 256, 0, stream>>>(Y, Wot, bo, (float*)d_out);
}

// Round 7
// 211.291 us; speedup vs baseline: 1.1090x; 1.1090x over previous
//
#include <hip/hip_runtime.h>
#include <hip/hip_bf16.h>
#include <math.h>

typedef __attribute__((ext_vector_type(8))) short short8;
typedef __attribute__((ext_vector_type(4))) float f32x4;
typedef __attribute__((ext_vector_type(4))) int int4v;

#define SCL 0.1803368801111204f   // 0.125 * log2(e): folds softmax scale + exp2 conversion

static __device__ __forceinline__ unsigned short f2bf(float f) {
  unsigned u = __float_as_uint(f);
  u = u + 0x7FFFu + ((u >> 16) & 1u);   // RNE
  return (unsigned short)(u >> 16);
}

// monotonic float<->uint key (no NaNs in data)
static __device__ __forceinline__ unsigned keyof(float x) {
  unsigned u = __float_as_uint(x);
  return (u & 0x80000000u) ? ~u : (u | 0x80000000u);
}
static __device__ __forceinline__ float keyinv(unsigned k) {
  unsigned u = (k & 0x80000000u) ? (k & 0x7FFFFFFFu) : ~k;
  return __uint_as_float(u);
}

// S: f32 [16][512] XOR-swizzled (32KB); P: bf16 [16][1024] aliased over the same 32KB.
// Row r of S and row r of P occupy the same 2KB stripe -> per-row self-aliasing only.
static __device__ __forceinline__ int saddr(int r, int cc) {
  return (((r << 9) + cc) << 2) ^ ((r & 7) << 4);
}
static __device__ __forceinline__ int paddr(int r, int c) {
  return ((r << 11) + (c << 1)) ^ ((r & 7) << 4);
}

// async global->LDS, 16B per lane (m97 pattern)
static __device__ __forceinline__ void gld_lds16(const unsigned short* g, unsigned short* l) {
  __builtin_amdgcn_global_load_lds(
      (const __attribute__((address_space(1))) void*)g,
      (__attribute__((address_space(3))) void*)l, 16, 0, 0);
}

// ---------------- f32 -> bf16, q/k/v fused (8/thread) ----------------
__global__ __launch_bounds__(256) void cvt3_k(const float* __restrict__ q,
                                              const float* __restrict__ k,
                                              const float* __restrict__ v,
                                              unsigned short* __restrict__ oq,
                                              unsigned short* __restrict__ ok,
                                              unsigned short* __restrict__ ov) {
  const int y = blockIdx.y;
  const float* in = (y == 0) ? q : (y == 1) ? k : v;
  unsigned short* out = (y == 0) ? oq : (y == 1) ? ok : ov;
  const int i = blockIdx.x * 256 + threadIdx.x;
  const f32x4* p = (const f32x4*)in + 2 * (size_t)i;
  f32x4 a = p[0], b = p[1];
  short8 r;
  r[0] = (short)f2bf(a[0]); r[1] = (short)f2bf(a[1]);
  r[2] = (short)f2bf(a[2]); r[3] = (short)f2bf(a[3]);
  r[4] = (short)f2bf(b[0]); r[5] = (short)f2bf(b[1]);
  r[6] = (short)f2bf(b[2]); r[7] = (short)f2bf(b[3]);
  ((short8*)out)[i] = r;
}

// ---------------- W [k][n] f32 -> Wt [n][k] bf16, 4 weights fused ----------------
__global__ __launch_bounds__(256) void wtrans4_k(const float* __restrict__ Wq,
                                                 const float* __restrict__ Wk,
                                                 const float* __restrict__ Wv,
                                                 const float* __restrict__ Wo,
                                                 unsigned short* __restrict__ Wqt,
                                                 unsigned short* __restrict__ Wkt,
                                                 unsigned short* __restrict__ Wvt,
                                                 unsigned short* __restrict__ Wot) {
  const int z = blockIdx.z;
  const float* W = (z == 0) ? Wq : (z == 1) ? Wk : (z == 2) ? Wv : Wo;
  unsigned short* Wt = (z == 0) ? Wqt : (z == 1) ? Wkt : (z == 2) ? Wvt : Wot;
  __shared__ float tile[32][33];
  const int tx = threadIdx.x, ty = threadIdx.y;
  const int x0 = blockIdx.x * 32, y0 = blockIdx.y * 32;
#pragma unroll
  for (int j = 0; j < 4; ++j)
    tile[ty + j * 8][tx] = W[(y0 + ty + j * 8) * 1024 + x0 + tx];
  __syncthreads();
#pragma unroll
  for (int j = 0; j < 4; ++j)
    Wt[(x0 + ty + j * 8) * 1024 + (y0 + tx)] = f2bf(tile[tx][ty + j * 8]);
}

// ---------------- 128x128 bf16 MFMA GEMM body, double-buffered LDS pipeline ----------------
// MODE 0: out bf16 [b][h][t][d]; MODE 1: out bf16 [b][h][d][t]; MODE 2: out f32 [m][n]
template <int MODE>
static __device__ __forceinline__ void gemm_body(unsigned short* As0, unsigned short* Bs0,
                                                 unsigned short* As1, unsigned short* Bs1,
                                                 const unsigned short* __restrict__ A,
                                                 const unsigned short* __restrict__ Bt,
                                                 const float* __restrict__ bias,
                                                 void* __restrict__ out) {
  const int tid = threadIdx.x;
  const int lane = tid & 63, w = tid >> 6;
  const int wr = w >> 1, wc = w & 1;
  const int m0 = blockIdx.y * 128, n0 = blockIdx.x * 128;
  const int l15 = lane & 15, l4 = lane >> 4;
  f32x4 acc[4][4] = {};
  const int r0 = tid >> 2, s0 = (tid & 3) * 8;
  const int r1 = r0 + 64;
  const unsigned short* gA0 = A + (m0 + r0) * 1024 + s0;
  const unsigned short* gA1 = A + (m0 + r1) * 1024 + s0;
  const unsigned short* gB0 = Bt + (n0 + r0) * 1024 + s0;
  const unsigned short* gB1 = Bt + (n0 + r1) * 1024 + s0;
  const int oA0 = r0 * 32 + s0, oA1 = r1 * 32 + s0;  // linear per-lane LDS offsets

  // prologue: stage kt=0 into buffer 0
  gld_lds16(gA0, As0 + oA0);
  gld_lds16(gA1, As0 + oA1);
  gld_lds16(gB0, Bs0 + oA0);
  gld_lds16(gB1, Bs0 + oA1);
  __syncthreads();

  for (int kt = 0; kt < 32; ++kt) {
    // prefetch next K-tile into the other buffer (latency hides under MFMA)
    if (kt < 31) {
      const int k0n = (kt + 1) * 32;
      unsigned short* Asn = (kt & 1) ? As0 : As1;
      unsigned short* Bsn = (kt & 1) ? Bs0 : Bs1;
      gld_lds16(gA0 + k0n, Asn + oA0);
      gld_lds16(gA1 + k0n, Asn + oA1);
      gld_lds16(gB0 + k0n, Bsn + oA0);
      gld_lds16(gB1 + k0n, Bsn + oA1);
    }
    const unsigned short* Asc = (kt & 1) ? As1 : As0;
    const unsigned short* Bsc = (kt & 1) ? Bs1 : Bs0;
    short8 af[4], bfr[4];
#pragma unroll
    for (int i = 0; i < 4; ++i) {
      af[i]  = *(const short8*)(Asc + (wr * 64 + i * 16 + l15) * 32 + l4 * 8);
      bfr[i] = *(const short8*)(Bsc + (wc * 64 + i * 16 + l15) * 32 + l4 * 8);
    }
#pragma unroll
    for (int i = 0; i < 4; ++i)
#pragma unroll
      for (int j = 0; j < 4; ++j)
        acc[i][j] = __builtin_amdgcn_mfma_f32_16x16x32_bf16(af[i], bfr[j], acc[i][j], 0, 0, 0);
    __syncthreads();   // drains prefetch vmcnt + protects buffer reuse
  }
#pragma unroll
  for (int i = 0; i < 4; ++i) {
#pragma unroll
    for (int j = 0; j < 4; ++j) {
      const int n = n0 + wc * 64 + j * 16 + l15;
      const float bv = bias[n];
#pragma unroll
      for (int r = 0; r < 4; ++r) {
        const int m = m0 + wr * 64 + i * 16 + l4 * 4 + r;
        const float v = acc[i][j][r] + bv;
        if (MODE == 2) {
          ((float*)out)[m * 1024 + n] = v;
        } else {
          const int bb = m >> 10, t = m & 1023, hh = n >> 6, dd = n & 63;
          const unsigned short bfv = f2bf(v);
          if (MODE == 0)
            ((unsigned short*)out)[(((bb << 4) + hh) * 1024 + t) * 64 + dd] = bfv;
          else
            ((unsigned short*)out)[(((bb << 4) + hh) * 64 + dd) * 1024 + t] = bfv;
        }
      }
    }
  }
}

__global__ __launch_bounds__(256) void gemm_qkv_k(
    const unsigned short* qbf, const unsigned short* kbf, const unsigned short* vbf,
    const unsigned short* Wqt, const unsigned short* Wkt, const unsigned short* Wvt,
    const float* bq, const float* bk, const float* bv,
    unsigned short* Qh, unsigned short* Kh, unsigned short* Vth) {
  __shared__ unsigned short As0[128 * 32], Bs0[128 * 32], As1[128 * 32], Bs1[128 * 32];
  const int z = blockIdx.z;
  const unsigned short* A  = (z == 0) ? qbf : ((z == 1) ? kbf : vbf);
  const unsigned short* Bt = (z == 0) ? Wqt : ((z == 1) ? Wkt : Wvt);
  const float* bias        = (z == 0) ? bq  : ((z == 1) ? bk  : bv);
  if (z == 2) gemm_body<1>(As0, Bs0, As1, Bs1, A, Bt, bias, Vth);
  else        gemm_body<0>(As0, Bs0, As1, Bs1, A, Bt, bias, z ? Kh : Qh);
}

__global__ __launch_bounds__(256) void gemm_out_k(const unsigned short* Y,
                                                  const unsigned short* Wot,
                                                  const float* bo, float* out) {
  __shared__ unsigned short As0[128 * 32], Bs0[128 * 32], As1[128 * 32], Bs1[128 * 32];
  gemm_body<2>(As0, Bs0, As1, Bs1, Y, Wot, bo, out);
}

// ---------------- attention phase 2: exact top-64 + unnormalized softmax -> P row ----------------
template <int NVAL>
static __device__ __forceinline__ void process_row(char* __restrict__ smem, float (&v)[NVAL],
                                                   const int r, const int Lr, const int Lpad,
                                                   const int lane, float* __restrict__ RED2) {
  float lm = v[0];
#pragma unroll
  for (int i = 1; i < NVAL; ++i) lm = fmaxf(lm, v[i]);
  float mx = lm;
#pragma unroll
  for (int o = 32; o; o >>= 1) mx = fmaxf(mx, __shfl_xor(mx, o));

  float thr = -INFINITY;
  if (Lr > 64) {                          // wave-uniform
    float mn = lm;
#pragma unroll
    for (int o = 32; o; o >>= 1) mn = fminf(mn, __shfl_xor(mn, o));
    // min-of-lane-maxes provably has count >= 64 (64 lane-max positions >= it;
    // lanes that are all--inf drag mn to -inf, which stays a valid lower bound)
    unsigned lo = (unsigned)__builtin_amdgcn_readfirstlane((int)keyof(mn));
    unsigned hi = (unsigned)__builtin_amdgcn_readfirstlane((int)keyof(mx)) + 1u;
    int cl = Lr, ch = 0, alt = 0;
    while (hi - lo > 1u) {
      const unsigned span = hi - lo;
      unsigned off;
      if (alt) off = span >> 1;
      else {
        const float fr = (float)(cl - 64) / (float)(cl - ch);
        off = (unsigned)(fr * (float)span);
        if (off < 1u) off = 1u;
        if (off > span - 1u) off = span - 1u;
      }
      alt ^= 1;
      const unsigned mid = lo + off;
      const float tm = keyinv(mid);
      int cnt = 0;
#pragma unroll
      for (int i = 0; i < NVAL; ++i) cnt += (int)__popcll(__ballot(v[i] >= tm));
      if (cnt >= 64) { lo = mid; cl = cnt; if (cnt == 64) break; }
      else { hi = mid; ch = cnt; }
    }
    thr = keyinv(lo);
  }

  float s = 0.f;
  unsigned pk[NVAL / 2];
#pragma unroll
  for (int p = 0; p < NVAL / 2; ++p) {
    const float p0 = (v[2 * p]     >= thr) ? exp2f(v[2 * p]     - mx) : 0.f;
    const float p1 = (v[2 * p + 1] >= thr) ? exp2f(v[2 * p + 1] - mx) : 0.f;
    s += p0 + p1;
    pk[p] = (unsigned)f2bf(p0) | ((unsigned)f2bf(p1) << 16);
  }
#pragma unroll
  for (int o = 32; o; o >>= 1) s += __shfl_xor(s, o);
  if (lane == 0) RED2[r] = 1.f / s;
#pragma unroll
  for (int p = 0; p < NVAL / 2; ++p) {
    const int c = ((p & 3) << 7) + (lane << 1) + ((p >= 4) ? 512 : 0);
    if (c < Lpad) *(unsigned*)(smem + paddr(r, c)) = pk[p];
  }
}

// ---------------- attention body, NVAL = 8 (L<=512) or 16 ----------------
template <int NVAL>
static __device__ __forceinline__ void attn_body(char* __restrict__ smem,
                                                 const unsigned short* __restrict__ Qp,
                                                 const unsigned short* __restrict__ Kh,
                                                 const unsigned short* __restrict__ Vh,
                                                 unsigned short* __restrict__ Y,
                                                 const int t0, const int h, const int b,
                                                 const int lane, const int w) {
  const int L = t0 + 16;
  const int Lpad = (L + 31) & ~31;
  const int nCT = L >> 4;
  const int l15 = lane & 15, l4 = lane >> 4;
  float* RED  = (float*)(smem + 32768);
  float* RED2 = (float*)(smem + 32768 + 4352);

  const short8 aq0 = *(const short8*)(Qp + l15 * 64 + l4 * 8);
  const short8 aq1 = *(const short8*)(Qp + l15 * 64 + 32 + l4 * 8);

  auto qk_chunk = [&](int tlo, int thi) {
    for (int ct = tlo + w; ct < thi; ct += 8) {
      const int c0 = ct * 16;
      const short8 kb0 = *(const short8*)(Kh + (c0 + l15) * 64 + l4 * 8);
      const short8 kb1 = *(const short8*)(Kh + (c0 + l15) * 64 + 32 + l4 * 8);
      f32x4 acc = {0.f, 0.f, 0.f, 0.f};
      acc = __builtin_amdgcn_mfma_f32_16x16x32_bf16(aq0, kb0, acc, 0, 0, 0);
      acc = __builtin_amdgcn_mfma_f32_16x16x32_bf16(aq1, kb1, acc, 0, 0, 0);
      const int c = c0 + l15, cc = c & 511;
      if (ct == nCT - 1) {           // only the diagonal tile needs masking (wave-uniform)
#pragma unroll
        for (int r = 0; r < 4; ++r) {
          const int row = l4 * 4 + r;
          *(float*)(smem + saddr(row, cc)) = (c <= t0 + row) ? acc[r] * SCL : -INFINITY;
        }
      } else {
#pragma unroll
        for (int r = 0; r < 4; ++r)
          *(float*)(smem + saddr(l4 * 4 + r, cc)) = acc[r] * SCL;
      }
    }
  };

  // ---- phase 1: S chunk 0 (cols [0,512)) ----
  qk_chunk(0, (nCT < 32) ? nCT : 32);
  __syncthreads();

  // ---- phase 2a: read chunk-0 halves of BOTH rows ----
  const int rA = w * 2, rB = rA + 1;
  const int LrA = t0 + rA + 1, LrB = t0 + rB + 1;
  float vA[NVAL], vB[NVAL];
#pragma unroll
  for (int p = 0; p < 4; ++p) {
    const int c = (p << 7) + (lane << 1);
    const float2 tA = *(const float2*)(smem + saddr(rA, c));
    const float2 tB = *(const float2*)(smem + saddr(rB, c));
    const bool vld = c < L;
    vA[2 * p]     = vld ? tA.x : -INFINITY;
    vA[2 * p + 1] = vld ? tA.y : -INFINITY;
    vB[2 * p]     = vld ? tB.x : -INFINITY;
    vB[2 * p + 1] = vld ? tB.y : -INFINITY;
  }

  if constexpr (NVAL == 16) {
    __syncthreads();              // chunk-0 reads complete
    qk_chunk(32, nCT);            // S chunk 1 (cols [512,1024)) into same LDS
    __syncthreads();
#pragma unroll
    for (int p = 0; p < 4; ++p) {
      const int cc = (p << 7) + (lane << 1);
      const float2 tA = *(const float2*)(smem + saddr(rA, cc));
      const bool vld = (cc + 512) < L;
      vA[8 + 2 * p] = vld ? tA.x : -INFINITY;
      vA[9 + 2 * p] = vld ? tA.y : -INFINITY;
    }
    process_row<NVAL>(smem, vA, rA, LrA, Lpad, lane, RED2);
#pragma unroll
    for (int p = 0; p < 4; ++p) {
      const int cc = (p << 7) + (lane << 1);
      const float2 tB = *(const float2*)(smem + saddr(rB, cc));
      const bool vld = (cc + 512) < L;
      vB[8 + 2 * p] = vld ? tB.x : -INFINITY;
      vB[9 + 2 * p] = vld ? tB.y : -INFINITY;
    }
    process_row<NVAL>(smem, vB, rB, LrB, Lpad, lane, RED2);
  } else {
    // P rows written by wave w alias only S rows 2w,2w+1 which only wave w reads
    process_row<NVAL>(smem, vA, rA, LrA, Lpad, lane, RED2);
    process_row<NVAL>(smem, vB, rB, LrB, Lpad, lane, RED2);
  }
  __syncthreads();

  // ---- phase 3: y = P @ V, K-split over all 8 waves + LDS reduction ----
  const int nST = Lpad >> 5;
  const int stMid = (nST + 1) >> 1;
  const int d0 = (w & 3) * 16;
  const int stLo = (w < 4) ? 0 : stMid;
  const int stHi = (w < 4) ? stMid : nST;
  f32x4 acc = {0.f, 0.f, 0.f, 0.f};
  for (int st = stLo; st < stHi; ++st) {
    const int sb = st * 32 + l4 * 8;
    const short8 paf = *(const short8*)(smem + paddr(l15, sb));
    const short8 vb = *(const short8*)(Vh + (d0 + l15) * 1024 + sb);
    acc = __builtin_amdgcn_mfma_f32_16x16x32_bf16(paf, vb, acc, 0, 0, 0);
  }
  if (w >= 4) {
    const int base = (w - 4) * 272 + l15;
#pragma unroll
    for (int r = 0; r < 4; ++r) RED[base + (l4 * 4 + r) * 17] = acc[r];
  }
  __syncthreads();
  if (w < 4) {
    const int base = w * 272 + l15;
    const int d = (h << 6) + d0 + l15;
#pragma unroll
    for (int r = 0; r < 4; ++r) {
      const float inv = RED2[l4 * 4 + r];
      const float vr = (acc[r] + RED[base + (l4 * 4 + r) * 17]) * inv;
      const int tg = t0 + l4 * 4 + r;
      Y[((b << 10) + tg) * 1024 + d] = f2bf(vr);
    }
  }
}

// grid (64 t-blocks, 16 heads, 4 batch), 512 threads (8 waves), 37.2KB dynamic LDS
__global__ __launch_bounds__(512, 6) void attn_k(const unsigned short* __restrict__ Q,
                                                 const unsigned short* __restrict__ K,
                                                 const unsigned short* __restrict__ Vt,
                                                 unsigned short* __restrict__ Y) {
  extern __shared__ __align__(16) char smem[];
  const int tid = threadIdx.x, lane = tid & 63, w = tid >> 6;
  const int t0 = (63 - (int)blockIdx.x) * 16;   // heavy blocks first
  const int h = blockIdx.y, b = blockIdx.z;
  const unsigned short* Qp = Q + (((b * 16 + h) * 1024) + t0) * 64;
  const unsigned short* Kh = K + (b * 16 + h) * 65536;
  const unsigned short* Vh = Vt + (b * 16 + h) * 65536;
  if (t0 >= 512) attn_body<16>(smem, Qp, Kh, Vh, Y, t0, h, b, lane, w);
  else           attn_body<8>(smem, Qp, Kh, Vh, Y, t0, h, b, lane, w);
}

// ---------------- host ----------------
extern "C" void kernel_launch(void* const* d_in, const int* in_sizes, int n_in,
                              void* d_out, int out_size, void* d_ws, size_t ws_size,
                              hipStream_t stream) {
  const float* q  = (const float*)d_in[0];
  const float* k  = (const float*)d_in[1];
  const float* v  = (const float*)d_in[2];
  // d_in[3] = tgt_mask (causal tril) — computed analytically, not read
  const float* Wq = (const float*)d_in[4];
  const float* Wk = (const float*)d_in[5];
  const float* Wv = (const float*)d_in[6];
  const float* Wo = (const float*)d_in[7];
  const float* bq = (const float*)d_in[8];
  const float* bk = (const float*)d_in[9];
  const float* bv = (const float*)d_in[10];
  const float* bo = (const float*)d_in[11];

  char* ws = (char*)d_ws;
  const size_t MB = 1u << 20;
  unsigned short* qbf = (unsigned short*)(ws + 0 * MB);   // 8MB; reused as Y later
  unsigned short* kbf = (unsigned short*)(ws + 8 * MB);   // 8MB
  unsigned short* vbf = (unsigned short*)(ws + 16 * MB);  // 8MB
  unsigned short* Wqt = (unsigned short*)(ws + 24 * MB);  // 2MB
  unsigned short* Wkt = (unsigned short*)(ws + 26 * MB);  // 2MB
  unsigned short* Wvt = (unsigned short*)(ws + 28 * MB);  // 2MB
  unsigned short* Wot = (unsigned short*)(ws + 30 * MB);  // 2MB
  unsigned short* Qh  = (unsigned short*)(ws + 32 * MB);  // 8MB [b][h][t][d]
  unsigned short* Kh  = (unsigned short*)(ws + 40 * MB);  // 8MB [b][h][t][d]
  unsigned short* Vth = (unsigned short*)(ws + 48 * MB);  // 8MB [b][h][d][t]
  unsigned short* Y   = qbf;  // alias: qbf is dead after gemm_qkv_k

  cvt3_k<<<dim3(2048, 3), 256, 0, stream>>>(q, k, v, qbf, kbf, vbf);
  wtrans4_k<<<dim3(32, 32, 4), dim3(32, 8), 0, stream>>>(Wq, Wk, Wv, Wo, Wqt, Wkt, Wvt, Wot);
  gemm_qkv_k<<<dim3(8, 32, 3), 256, 0, stream>>>(qbf, kbf, vbf, Wqt, Wkt, Wvt,
                                                 bq, bk, bv, Qh, Kh, Vth);
  attn_k<<<dim3(64, 16, 4), 512, 37248, stream>>>(Qh, Kh, Vth, Y);
  gemm_out_k<<<dim3(8, 32), 256, 0, stream>>>(Y, Wot, bo, (float*)d_out);
}